// Round 1
// baseline (75.269 us; speedup 1.0000x reference)
//
#include <hip/hip_runtime.h>
#include <math.h>

#define RADIUS 0.05f
#define NTHREADS 256      // 4 waves/block, 4 blocks/CU at grid=1024 -> cross-block overlap
#define TSZ      4        // 4x4 pixel tile
#define NPIX     16       // pixels per tile
#define NSLICE   16       // point-slices per tile
#define SPCAP   192       // per-tile candidate capacity (E~27; overflow P negligible)
#define HCAP    40        // per-pixel hit capacity (E=8, Poisson tail ~1e-18)
#define HSTR    41        // stride 41 dwords: gcd(41 mod 32 = 9, 32)=1 -> conflict-free

// One block = one 4x4 pixel tile, 256 threads = 16 pixels x 16 point-slices.
// 1024 blocks -> 4 blocks/CU so phases of different blocks overlap (latency hiding);
// previous 8x8/1024-thread config had 1 block/CU and fully serialized phases.
// Phase 1: div-free cull of all N points, 4 points per 3 float4 loads.
// Phase 2: sliced scan (16 slices), hits appended to per-pixel LDS lists.
// Phase 3: 4 pixels on lanes 0-3 of EACH of the 4 waves (4 SIMDs active, not 1):
//          top-8-by-z insertion, composite, store.
__global__ __launch_bounds__(NTHREADS) void render_tiles(
    const float* __restrict__ points,    // [N,3] camera space
    const float* __restrict__ features,  // [N,8]
    float* __restrict__ out,             // [H,W,8]
    int N, int H, int W, int tiles_x)
{
    const float r2 = RADIUS * RADIUS;
    const float inv_r2 = 1.0f / r2;

    __shared__ float4 sp[SPCAP];          // (px, py, z, idx-as-float)
    __shared__ float  s_hz[NPIX * HSTR];
    __shared__ float  s_hd[NPIX * HSTR];
    __shared__ int    s_hi[NPIX * HSTR];
    __shared__ int    s_pcnt[NPIX];
    __shared__ int    s_cnt;

    const int tid = threadIdx.x;
    if (tid == 0) s_cnt = 0;
    if (tid < NPIX) s_pcnt[tid] = 0;
    __syncthreads();

    const int tile = blockIdx.x;
    const int tx = tile % tiles_x;
    const int ty = tile / tiles_x;
    const int x0i = tx * TSZ, y0i = ty * TSZ;
    const float sx = 2.0f / (float)W, sy = 2.0f / (float)H;
    // tile pixel-center NDC bounds, expanded by splat radius (conservative)
    const float bx0 = ((float)x0i + 0.5f) * sx - 1.0f - RADIUS;
    const float bx1 = ((float)(x0i + TSZ - 1) + 0.5f) * sx - 1.0f + RADIUS;
    const float by0 = ((float)y0i + 0.5f) * sy - 1.0f - RADIUS;
    const float by1 = ((float)(y0i + TSZ - 1) + 0.5f) * sy - 1.0f + RADIUS;

    // ---- Phase 1: vectorized div-free cull (px>=bx0 <=> x>=bx0*z since z>0) ----
    // 4 points = 48 B = 3 x float4 per iteration.
    const float4* p4 = (const float4*)points;
    const int N4 = N & ~3;
    for (int i0 = tid * 4; i0 < N4; i0 += NTHREADS * 4) {
        const int q = 3 * (i0 >> 2);
        float4 a = p4[q + 0];
        float4 b = p4[q + 1];
        float4 c = p4[q + 2];
        const float xs_[4] = {a.x, a.w, b.z, c.y};
        const float ys_[4] = {a.y, b.x, b.w, c.z};
        const float zs_[4] = {a.z, b.y, c.x, c.w};
#pragma unroll
        for (int j = 0; j < 4; j++) {
            float x = xs_[j], y = ys_[j], z = zs_[j];
            bool keep = (z > 0.0f) & (x >= bx0 * z) & (x <= bx1 * z)
                                   & (y >= by0 * z) & (y <= by1 * z);
            if (keep) {
                float rz = __builtin_amdgcn_rcpf(z);   // ~1ulp; error << alpha threshold
                int pos = atomicAdd(&s_cnt, 1);
                if (pos < SPCAP)
                    sp[pos] = make_float4(x * rz, y * rz, z, __int_as_float(i0 + j));
            }
        }
    }
    // scalar tail (N % 4 != 0); no-op for N=4096
    for (int i = N4 + tid; i < N; i += NTHREADS) {
        float x = points[3 * i + 0];
        float y = points[3 * i + 1];
        float z = points[3 * i + 2];
        bool keep = (z > 0.0f) & (x >= bx0 * z) & (x <= bx1 * z)
                               & (y >= by0 * z) & (y <= by1 * z);
        if (keep) {
            float rz = __builtin_amdgcn_rcpf(z);
            int pos = atomicAdd(&s_cnt, 1);
            if (pos < SPCAP) sp[pos] = make_float4(x * rz, y * rz, z, __int_as_float(i));
        }
    }
    __syncthreads();
    const int cnt = min(s_cnt, SPCAP);

    // ---- Phase 2: sliced scan, append hits per pixel (pipelined LDS reads) ----
    const int pxl = tid & 15;
    const int slice = tid >> 4;   // 0..15
    const int ix = x0i + (pxl & 3);
    const int iy = y0i + (pxl >> 2);
    const float gx = ((float)ix + 0.5f) * sx - 1.0f;
    const float gy = ((float)iy + 0.5f) * sy - 1.0f;

    int c = slice;
    if (c < cnt) {
        float4 q = sp[c];                 // 4 consecutive float4s per wave: conflict-free
        while (true) {
            int cn = c + NSLICE;
            bool more = cn < cnt;
            float4 qn = sp[more ? cn : slice];   // prefetch next before processing
            float dx = gx - q.x;
            float dy = gy - q.y;
            float d2 = dx * dx + dy * dy;
            if (d2 < r2) {
                int pos = atomicAdd(&s_pcnt[pxl], 1);
                if (pos < HCAP) {
                    s_hz[pxl * HSTR + pos] = q.z;
                    s_hd[pxl * HSTR + pos] = d2;
                    s_hi[pxl * HSTR + pos] = __float_as_int(q.w);
                }
            }
            if (!more) break;
            q = qn; c = cn;
        }
    }
    __syncthreads();

    // ---- Phase 3: per-pixel top-8 by depth + composite ----
    // 4 pixels per wave on lanes 0-3 -> all 4 SIMDs work the serial tail concurrently.
    const int lane = tid & 63;
    const int wave = tid >> 6;            // 0..3
    if (lane < 4) {
        const int p = wave * 4 + lane;    // 0..15
        const int m = min(s_pcnt[p], HCAP);
        float zk[8];
        int sk[8];
#pragma unroll
        for (int k = 0; k < 8; k++) { zk[k] = 3.0e38f; sk[k] = 0; }

        float z_next = s_hz[p * HSTR];              // safe: garbage if m==0, unused
        for (int i = 0; i < m; i++) {
            float z = z_next;
            z_next = s_hz[p * HSTR + i + 1];        // prefetch (i+1 <= HCAP, in-bounds)
            if (z < zk[7]) {
                int s = i;
#pragma unroll
                for (int k = 0; k < 8; k++) {
                    bool lt = z < zk[k];   // strict <, z distinct -> order-independent
                    float tz = zk[k];
                    int ts = sk[k];
                    if (lt) { zk[k] = z; sk[k] = s; z = tz; s = ts; }
                }
            }
        }

        float acc0 = 0.f, acc1 = 0.f, acc2 = 0.f, acc3 = 0.f;
        float acc4 = 0.f, acc5 = 0.f, acc6 = 0.f, acc7 = 0.f;
        float T = 1.0f;
#pragma unroll
        for (int k = 0; k < 8; k++) {
            if (zk[k] < 1.0e30f) {
                float d2 = s_hd[p * HSTR + sk[k]];
                int   id = s_hi[p * HSTR + sk[k]];
                float alpha = 1.0f - d2 * inv_r2;
                alpha = fminf(fmaxf(alpha, 0.0f), 1.0f);
                float w = alpha * T;
                T *= (1.0f - alpha);
                const float4* f = (const float4*)(features + (size_t)id * 8);
                float4 f0 = f[0];
                float4 f1 = f[1];
                acc0 += w * f0.x; acc1 += w * f0.y; acc2 += w * f0.z; acc3 += w * f0.w;
                acc4 += w * f1.x; acc5 += w * f1.y; acc6 += w * f1.z; acc7 += w * f1.w;
            }
        }

        const int oix = x0i + (p & 3);
        const int oiy = y0i + (p >> 2);
        if (oix < W && oiy < H) {
            float4* o = (float4*)(out + (size_t)(oiy * W + oix) * 8);
            o[0] = make_float4(acc0, acc1, acc2, acc3);
            o[1] = make_float4(acc4, acc5, acc6, acc7);
        }
    }
}

extern "C" void kernel_launch(void* const* d_in, const int* in_sizes, int n_in,
                              void* d_out, int out_size, void* d_ws, size_t ws_size,
                              hipStream_t stream) {
    const float* points = (const float*)d_in[0];
    const float* features = (const float*)d_in[1];
    float* out = (float*)d_out;

    int N = in_sizes[0] / 3;                // 4096
    int C = in_sizes[1] / N;                // 8 (kernel assumes 8)
    int P = out_size / C;                   // 16384
    int H = (int)(sqrt((double)P) + 0.5);   // 128
    int W = H;
    int tiles_x = (W + TSZ - 1) / TSZ;      // 32
    int tiles_y = (H + TSZ - 1) / TSZ;      // 32

    render_tiles<<<tiles_x * tiles_y, NTHREADS, 0, stream>>>(points, features, out,
                                                             N, H, W, tiles_x);
}

// Round 2
// 69.543 us; speedup vs baseline: 1.0823x; 1.0823x over previous
//
#include <hip/hip_runtime.h>
#include <math.h>

#define RADIUS 0.05f
#define NTHREADS 1024     // 16 waves/block, grid=256 -> 1 block/CU, minimum scan redundancy
#define TSZ      8        // 8x8 pixel tile (measured best: 70.5us vs 75.3us for 4x4)
#define NPIX     64       // pixels per tile
#define NSLICE   16       // point-slices per tile = waves per block
#define SPCAP   256       // per-tile candidate capacity (E~67; overflow P ~ e^-46)
#define HCAP    40        // per-pixel hit capacity (E=8, Poisson tail ~1e-18)
#define HSTR    41        // stride 41 dwords: 41 mod 32 = 9, gcd(9,32)=1 -> conflict-free

// One block = one 8x8 pixel tile, 1024 threads = 64 pixels x 16 point-slices.
// 256 blocks: each block scans all N points once; round-1 showed scan redundancy
// (1024 blocks) costs ~+4.8us -- keep it at the 256-block minimum.
// Phase 1: div-free cull, 4 points per 3 float4 loads (1 iteration/thread at N=4096).
// Phase 2: sliced scan (16 slices), hits appended to per-pixel LDS lists.
// Phase 3: 64 pixels spread over waves 0-3, lanes 0-15 (4 SIMDs work the serial
//          top-8-by-z + composite tail concurrently instead of 1).
__global__ __launch_bounds__(NTHREADS) void render_tiles(
    const float* __restrict__ points,    // [N,3] camera space
    const float* __restrict__ features,  // [N,8]
    float* __restrict__ out,             // [H,W,8]
    int N, int H, int W, int tiles_x)
{
    const float r2 = RADIUS * RADIUS;
    const float inv_r2 = 1.0f / r2;

    __shared__ float4 sp[SPCAP];          // (px, py, z, idx-as-float)
    __shared__ float  s_hz[NPIX * HSTR];
    __shared__ float  s_hd[NPIX * HSTR];
    __shared__ int    s_hi[NPIX * HSTR];
    __shared__ int    s_pcnt[NPIX];
    __shared__ int    s_cnt;

    const int tid = threadIdx.x;
    if (tid == 0) s_cnt = 0;
    if (tid < NPIX) s_pcnt[tid] = 0;
    __syncthreads();

    const int tile = blockIdx.x;
    const int tx = tile % tiles_x;
    const int ty = tile / tiles_x;
    const int x0i = tx * TSZ, y0i = ty * TSZ;
    const float sx = 2.0f / (float)W, sy = 2.0f / (float)H;
    // tile pixel-center NDC bounds, expanded by splat radius (conservative)
    const float bx0 = ((float)x0i + 0.5f) * sx - 1.0f - RADIUS;
    const float bx1 = ((float)(x0i + TSZ - 1) + 0.5f) * sx - 1.0f + RADIUS;
    const float by0 = ((float)y0i + 0.5f) * sy - 1.0f - RADIUS;
    const float by1 = ((float)(y0i + TSZ - 1) + 0.5f) * sy - 1.0f + RADIUS;

    // ---- Phase 1: vectorized div-free cull (px>=bx0 <=> x>=bx0*z since z>0) ----
    // 4 points = 48 B = 3 x float4; at N=4096/1024 threads: exactly 1 iter/thread.
    const float4* p4 = (const float4*)points;
    const int N4 = N & ~3;
    for (int i0 = tid * 4; i0 < N4; i0 += NTHREADS * 4) {
        const int q = 3 * (i0 >> 2);
        float4 a = p4[q + 0];
        float4 b = p4[q + 1];
        float4 c = p4[q + 2];
        const float xs_[4] = {a.x, a.w, b.z, c.y};
        const float ys_[4] = {a.y, b.x, b.w, c.z};
        const float zs_[4] = {a.z, b.y, c.x, c.w};
#pragma unroll
        for (int j = 0; j < 4; j++) {
            float x = xs_[j], y = ys_[j], z = zs_[j];
            bool keep = (z > 0.0f) & (x >= bx0 * z) & (x <= bx1 * z)
                                   & (y >= by0 * z) & (y <= by1 * z);
            if (keep) {
                float rz = __builtin_amdgcn_rcpf(z);   // ~1ulp; error << alpha threshold
                int pos = atomicAdd(&s_cnt, 1);
                if (pos < SPCAP)
                    sp[pos] = make_float4(x * rz, y * rz, z, __int_as_float(i0 + j));
            }
        }
    }
    // scalar tail (N % 4 != 0); no-op for N=4096
    for (int i = N4 + tid; i < N; i += NTHREADS) {
        float x = points[3 * i + 0];
        float y = points[3 * i + 1];
        float z = points[3 * i + 2];
        bool keep = (z > 0.0f) & (x >= bx0 * z) & (x <= bx1 * z)
                               & (y >= by0 * z) & (y <= by1 * z);
        if (keep) {
            float rz = __builtin_amdgcn_rcpf(z);
            int pos = atomicAdd(&s_cnt, 1);
            if (pos < SPCAP) sp[pos] = make_float4(x * rz, y * rz, z, __int_as_float(i));
        }
    }
    __syncthreads();
    const int cnt = min(s_cnt, SPCAP);

    // ---- Phase 2: sliced scan, append hits per pixel (pipelined LDS reads) ----
    const int pxl = tid & 63;
    const int slice = tid >> 6;   // 0..15
    const int ix = x0i + (pxl & 7);
    const int iy = y0i + (pxl >> 3);
    const float gx = ((float)ix + 0.5f) * sx - 1.0f;
    const float gy = ((float)iy + 0.5f) * sy - 1.0f;

    int c = slice;
    if (c < cnt) {
        float4 q = sp[c];                 // broadcast across wave, conflict-free
        while (true) {
            int cn = c + NSLICE;
            bool more = cn < cnt;
            float4 qn = sp[more ? cn : slice];   // prefetch next before processing
            float dx = gx - q.x;
            float dy = gy - q.y;
            float d2 = dx * dx + dy * dy;
            if (d2 < r2) {
                int pos = atomicAdd(&s_pcnt[pxl], 1);
                if (pos < HCAP) {
                    s_hz[pxl * HSTR + pos] = q.z;
                    s_hd[pxl * HSTR + pos] = d2;
                    s_hi[pxl * HSTR + pos] = __float_as_int(q.w);
                }
            }
            if (!more) break;
            q = qn; c = cn;
        }
    }
    __syncthreads();

    // ---- Phase 3: per-pixel top-8 by depth + composite ----
    // waves 0-3, lanes 0-15: 16 pixels/wave -> all 4 SIMDs run the serial tail.
    const int wv = tid >> 6;              // 0..15
    const int ln = tid & 63;
    if (wv < 4 && ln < 16) {
        const int p = wv * 16 + ln;       // 0..63
        const int m = min(s_pcnt[p], HCAP);
        float zk[8];
        int sk[8];
#pragma unroll
        for (int k = 0; k < 8; k++) { zk[k] = 3.0e38f; sk[k] = 0; }

        float z_next = s_hz[p * HSTR];              // safe: garbage if m==0, unused
        for (int i = 0; i < m; i++) {
            float z = z_next;
            z_next = s_hz[p * HSTR + i + 1];        // prefetch (i+1 <= HCAP, in-bounds)
            if (z < zk[7]) {
                int s = i;
#pragma unroll
                for (int k = 0; k < 8; k++) {
                    bool lt = z < zk[k];   // strict <, z distinct -> order-independent
                    float tz = zk[k];
                    int ts = sk[k];
                    if (lt) { zk[k] = z; sk[k] = s; z = tz; s = ts; }
                }
            }
        }

        float acc0 = 0.f, acc1 = 0.f, acc2 = 0.f, acc3 = 0.f;
        float acc4 = 0.f, acc5 = 0.f, acc6 = 0.f, acc7 = 0.f;
        float T = 1.0f;
#pragma unroll
        for (int k = 0; k < 8; k++) {
            if (zk[k] < 1.0e30f) {
                float d2 = s_hd[p * HSTR + sk[k]];
                int   id = s_hi[p * HSTR + sk[k]];
                float alpha = 1.0f - d2 * inv_r2;
                alpha = fminf(fmaxf(alpha, 0.0f), 1.0f);
                float w = alpha * T;
                T *= (1.0f - alpha);
                const float4* f = (const float4*)(features + (size_t)id * 8);
                float4 f0 = f[0];
                float4 f1 = f[1];
                acc0 += w * f0.x; acc1 += w * f0.y; acc2 += w * f0.z; acc3 += w * f0.w;
                acc4 += w * f1.x; acc5 += w * f1.y; acc6 += w * f1.z; acc7 += w * f1.w;
            }
        }

        const int oix = x0i + (p & 7);
        const int oiy = y0i + (p >> 3);
        if (oix < W && oiy < H) {
            float4* o = (float4*)(out + (size_t)(oiy * W + oix) * 8);
            o[0] = make_float4(acc0, acc1, acc2, acc3);
            o[1] = make_float4(acc4, acc5, acc6, acc7);
        }
    }
}

extern "C" void kernel_launch(void* const* d_in, const int* in_sizes, int n_in,
                              void* d_out, int out_size, void* d_ws, size_t ws_size,
                              hipStream_t stream) {
    const float* points = (const float*)d_in[0];
    const float* features = (const float*)d_in[1];
    float* out = (float*)d_out;

    int N = in_sizes[0] / 3;                // 4096
    int C = in_sizes[1] / N;                // 8 (kernel assumes 8)
    int P = out_size / C;                   // 16384
    int H = (int)(sqrt((double)P) + 0.5);   // 128
    int W = H;
    int tiles_x = (W + TSZ - 1) / TSZ;      // 16
    int tiles_y = (H + TSZ - 1) / TSZ;      // 16

    render_tiles<<<tiles_x * tiles_y, NTHREADS, 0, stream>>>(points, features, out,
                                                             N, H, W, tiles_x);
}